// Round 16
// baseline (1157.818 us; speedup 1.0000x reference)
//
#include <hip/hip_runtime.h>

// CfC actor-critic forward: B=256, T=1024, OBS=32, H=128, A=8.
// R16 = R15 + two latency-chain cuts:
//  (1) px = x @ Wb_x precomputed per block into d_ws (prologue GEMM):
//      the backbone recurrence drops to K=128 (4 MFMAs, 2 chains of 2),
//      one less ds_read, and the per-step obs/x-ring machinery (straggler
//      waves 0-1) is deleted. Each lane loads its single px f16 value
//      (row=hi, col=colB -- the post-redistribution coordinate) 2 steps
//      ahead, fire-and-forget past the lgkm-only barriers.
//  (2) ph2 gate chains split depth 4 -> 2 (6 accumulators, +12 adds).
// MODE2: px+hist (ws>=134MB); MODE1: R15 behavior (ws>=67MB); MODE0: in-loop.

typedef _Float16 half8 __attribute__((ext_vector_type(8)));
typedef float f32x4 __attribute__((ext_vector_type(4)));

#define T_STEPS 1024
#define OBS 32
#define H 128
#define A_DIM 8
#define NW 8
#define NT (NW * 64)
#define ROWS 4
#define NBLK 64

#define ZIN_P 164   // stride 82 words (mod 32 = 18) -> <=2-way banks
#define ZF_P 132    // stride 66 words (mod 32 = 2)

__device__ __forceinline__ float fexp2(float x) { return __builtin_amdgcn_exp2f(x); }
__device__ __forceinline__ float frcp(float x) { return __builtin_amdgcn_rcpf(x); }

// LDS-visibility barrier (no vmcnt drain; validated R10)
__device__ __forceinline__ void sync_lds() {
    __builtin_amdgcn_sched_barrier(0);
    asm volatile("s_waitcnt lgkmcnt(0)" ::: "memory");
    __builtin_amdgcn_s_barrier();
    __builtin_amdgcn_sched_barrier(0);
}

template<int MODE>   // 2: px+hist, 1: hist only (R15), 0: no ws
__global__ void __launch_bounds__(NT) cfc_kernel(
    const float* __restrict__ obs,
    const float* __restrict__ Wb,  const float* __restrict__ bb,
    const float* __restrict__ Wff1, const float* __restrict__ bff1,
    const float* __restrict__ Wff2, const float* __restrict__ bff2,
    const float* __restrict__ Wta, const float* __restrict__ bta,
    const float* __restrict__ Wtb, const float* __restrict__ btb,
    const float* __restrict__ Wa,  const float* __restrict__ ba,
    const float* __restrict__ Wc,  const float* __restrict__ bc,
    float* __restrict__ out_mean, float* __restrict__ out_value,
    _Float16* __restrict__ hist, _Float16* __restrict__ pxw)
{
    constexpr int HOFF = (MODE == 2) ? 0 : 32;   // h offset inside zin
    const int b0 = blockIdx.x * ROWS;
    const int tid = threadIdx.x;
    const int w = tid >> 6, l = tid & 63;
    const int lo = l & 15, hi = l >> 4;

    __shared__ _Float16 zin[16][ZIN_P];      // MODE2: h only; else [x|h]
    __shared__ _Float16 zf[16][ZF_P];        // z(t)

    // ---------------- preload B-fragments (f16) ----------------
    const int colB = w * 16 + lo;

    half8 Bb[5];                              // MODE2: Bb[0..3] = h-k 32..159
    half8 BbX;                                // MODE2: x-k 0..31 (prologue only)
    if constexpr (MODE == 2) {
#pragma unroll
        for (int j = 0; j < 8; ++j) BbX[j] = (_Float16)Wb[(hi * 8 + j) * H + colB];
#pragma unroll
        for (int ks = 0; ks < 4; ++ks)
#pragma unroll
            for (int j = 0; j < 8; ++j) {
                int k = (ks + 1) * 32 + hi * 8 + j;
                Bb[ks][j] = (_Float16)Wb[k * H + colB];
            }
    } else {
#pragma unroll
        for (int ks = 0; ks < 5; ++ks)
#pragma unroll
            for (int j = 0; j < 8; ++j) {
                int k = ks * 32 + hi * 8 + j;
                Bb[ks][j] = (_Float16)Wb[k * H + colB];
            }
    }
    const float bbv = bb[colB];

    half8 Bg0[4], Bg1[4], Bg2[4];             // gates HxH
#pragma unroll
    for (int ks = 0; ks < 4; ++ks)
#pragma unroll
        for (int j = 0; j < 8; ++j) {
            int k = ks * 32 + hi * 8 + j;
            Bg0[ks][j] = (_Float16)Wff1[k * H + colB];
            Bg1[ks][j] = (_Float16)Wff2[k * H + colB];
            Bg2[ks][j] = (_Float16)(Wta[k * H + colB] + Wtb[k * H + colB]);
        }
    const float bg1 = bff1[colB], bg2 = bff2[colB], bg3 = bta[colB] + btb[colB];

    half8 Bh[4];                              // in-loop heads (MODE0, wave 7)
    float bh = 0.f;
    if (MODE == 0 && w == 7) {
#pragma unroll
        for (int ks = 0; ks < 4; ++ks)
#pragma unroll
            for (int j = 0; j < 8; ++j) {
                int k = ks * 32 + hi * 8 + j;
                float v = (lo < 8) ? Wa[k * A_DIM + lo] : ((lo == 8) ? Wc[k] : 0.0f);
                Bh[ks][j] = (_Float16)v;
            }
        bh = (lo < 8) ? ba[lo] : ((lo == 8) ? bc[0] : 0.0f);
    }

    // ---------------- init LDS (garbage rows stay zero) ----------------
    for (int i = tid; i < 16 * ZIN_P; i += NT) (&zin[0][0])[i] = (_Float16)0.0f;
    for (int i = tid; i < 16 * ZF_P; i += NT) (&zf[0][0])[i] = (_Float16)0.0f;
    __syncthreads();

    // ---------------- MODE2 prologue: px = x @ Wb_x for this block --------
    float pxU = 0.f, pxV = 0.f;
    const _Float16* pxL = nullptr;
    if constexpr (MODE == 2) {
        for (int r = 0; r < ROWS; ++r) {
            for (int tc = 0; tc < T_STEPS / 16; ++tc) {
                const float* xp = obs + ((size_t)(b0 + r) * T_STEPS + tc * 16 + lo) * OBS + hi * 8;
                float4 xa = *(const float4*)xp;
                float4 xb = *(const float4*)(xp + 4);
                half8 Ax;
                Ax[0] = (_Float16)xa.x; Ax[1] = (_Float16)xa.y;
                Ax[2] = (_Float16)xa.z; Ax[3] = (_Float16)xa.w;
                Ax[4] = (_Float16)xb.x; Ax[5] = (_Float16)xb.y;
                Ax[6] = (_Float16)xb.z; Ax[7] = (_Float16)xb.w;
                f32x4 acc = {0.f, 0.f, 0.f, 0.f};
                acc = __builtin_amdgcn_mfma_f32_16x16x32_f16(Ax, BbX, acc, 0, 0, 0);
#pragma unroll
                for (int jj = 0; jj < 4; ++jj)
                    pxw[((size_t)(b0 + r) * T_STEPS + tc * 16 + hi * 4 + jj) * H + colB] = (_Float16)acc[jj];
            }
        }
        __syncthreads();                       // px visible (vmcnt drained)
        pxL = pxw + ((size_t)(b0 + hi) * T_STEPS) * H + colB;
        pxU = (float)pxL[0];
        pxV = (float)pxL[(size_t)1 * H];
    }

    // ---------------- MODE<2: x(0) + obs ring (waves 0-1) ----------------
    const int rX = (w << 1) | (l >> 5), cX = l & 31;
    float oxA = 0.f, oxB = 0.f;
    if constexpr (MODE < 2) {
        if (w < 2) {
            zin[rX][cX] = (_Float16)obs[((size_t)(b0 + rX) * T_STEPS) * OBS + cX];
            oxA = obs[((size_t)(b0 + rX) * T_STEPS + 1) * OBS + cX];
            oxB = obs[((size_t)(b0 + rX) * T_STEPS + 2) * OBS + cX];
        }
        __syncthreads();
    }

    const int srcl = lo;                      // shuffle source lane (hi==0, same col)

    // ================= main loop: 2 LDS-only barriers/step =================
    for (int t = 0; t < T_STEPS; ++t) {
        // ---- phase 1: z = lecun_tanh(px + h @ Wb_h + bb) ----
        if constexpr (MODE == 2) {
            half8 A1 = *(const half8*)&zin[lo][0 * 32 + hi * 8];
            half8 A2 = *(const half8*)&zin[lo][1 * 32 + hi * 8];
            half8 A3 = *(const half8*)&zin[lo][2 * 32 + hi * 8];
            half8 A4 = *(const half8*)&zin[lo][3 * 32 + hi * 8];
            f32x4 az0 = {bbv, bbv, bbv, bbv};
            f32x4 az1 = {0.f, 0.f, 0.f, 0.f};
            az0 = __builtin_amdgcn_mfma_f32_16x16x32_f16(A1, Bb[0], az0, 0, 0, 0);
            az1 = __builtin_amdgcn_mfma_f32_16x16x32_f16(A2, Bb[1], az1, 0, 0, 0);
            az0 = __builtin_amdgcn_mfma_f32_16x16x32_f16(A3, Bb[2], az0, 0, 0, 0);
            az1 = __builtin_amdgcn_mfma_f32_16x16x32_f16(A4, Bb[3], az1, 0, 0, 0);

            float s0 = az0[0] + az1[0];
            float s1 = az0[1] + az1[1];
            float s2 = az0[2] + az1[2];
            float s3 = az0[3] + az1[3];
            float p0 = __shfl(s0, srcl), p1 = __shfl(s1, srcl);
            float p2 = __shfl(s2, srcl), p3 = __shfl(s3, srcl);
            float q01 = (hi & 1) ? p1 : p0;
            float q23 = (hi & 1) ? p3 : p2;
            float sv  = ((hi & 2) ? q23 : q01) + pxU;
            float r = frcp(fexp2(1.9216697f * sv) + 1.0f);
            zf[hi][colB] = (_Float16)fmaf(-3.4318f, r, 1.7159f);

            pxU = pxV;                         // advance px ring (loads stay in flight)
            pxV = (t + 2 < T_STEPS) ? (float)pxL[(size_t)(t + 2) * H] : 0.0f;
        } else {
            half8 A0 = *(const half8*)&zin[lo][0 * 32 + hi * 8];
            half8 A1 = *(const half8*)&zin[lo][1 * 32 + hi * 8];
            half8 A2 = *(const half8*)&zin[lo][2 * 32 + hi * 8];
            half8 A3 = *(const half8*)&zin[lo][3 * 32 + hi * 8];
            half8 A4 = *(const half8*)&zin[lo][4 * 32 + hi * 8];
            f32x4 az0 = {bbv, bbv, bbv, bbv};
            f32x4 az1 = {0.f, 0.f, 0.f, 0.f};
            az0 = __builtin_amdgcn_mfma_f32_16x16x32_f16(A0, Bb[0], az0, 0, 0, 0);
            az1 = __builtin_amdgcn_mfma_f32_16x16x32_f16(A1, Bb[1], az1, 0, 0, 0);
            az0 = __builtin_amdgcn_mfma_f32_16x16x32_f16(A2, Bb[2], az0, 0, 0, 0);
            az1 = __builtin_amdgcn_mfma_f32_16x16x32_f16(A3, Bb[3], az1, 0, 0, 0);
            az0 = __builtin_amdgcn_mfma_f32_16x16x32_f16(A4, Bb[4], az0, 0, 0, 0);

            if (MODE == 0 && w == 7 && t > 0) {
                f32x4 acch = {bh, bh, bh, bh};
                acch = __builtin_amdgcn_mfma_f32_16x16x32_f16(A1, Bh[0], acch, 0, 0, 0);
                acch = __builtin_amdgcn_mfma_f32_16x16x32_f16(A2, Bh[1], acch, 0, 0, 0);
                acch = __builtin_amdgcn_mfma_f32_16x16x32_f16(A3, Bh[2], acch, 0, 0, 0);
                acch = __builtin_amdgcn_mfma_f32_16x16x32_f16(A4, Bh[3], acch, 0, 0, 0);
                if (hi == 0 && lo < 9) {
#pragma unroll
                    for (int j = 0; j < 4; ++j) {
                        if (lo < 8) out_mean[((size_t)(b0 + j) * T_STEPS + (t - 1)) * A_DIM + lo] = acch[j];
                        else        out_value[(size_t)(b0 + j) * T_STEPS + (t - 1)] = acch[j];
                    }
                }
            }

            float s0 = az0[0] + az1[0];
            float s1 = az0[1] + az1[1];
            float s2 = az0[2] + az1[2];
            float s3 = az0[3] + az1[3];
            float p0 = __shfl(s0, srcl), p1 = __shfl(s1, srcl);
            float p2 = __shfl(s2, srcl), p3 = __shfl(s3, srcl);
            float q01 = (hi & 1) ? p1 : p0;
            float q23 = (hi & 1) ? p3 : p2;
            float sv  = (hi & 2) ? q23 : q01;
            float r = frcp(fexp2(1.9216697f * sv) + 1.0f);
            zf[hi][colB] = (_Float16)fmaf(-3.4318f, r, 1.7159f);
        }
        sync_lds();

        // ---- phase 2: gates + combine -> h(t) ----
        half8 Z0 = *(const half8*)&zf[lo][0 * 32 + hi * 8];
        half8 Z1 = *(const half8*)&zf[lo][1 * 32 + hi * 8];
        half8 Z2 = *(const half8*)&zf[lo][2 * 32 + hi * 8];
        half8 Z3 = *(const half8*)&zf[lo][3 * 32 + hi * 8];

        float v1, v2, v3;
        if constexpr (MODE == 2) {
            // depth-2 chains: 6 accumulators
            f32x4 a1a = {bg1, bg1, bg1, bg1}, a1b = {0.f, 0.f, 0.f, 0.f};
            f32x4 a2a = {bg2, bg2, bg2, bg2}, a2b = {0.f, 0.f, 0.f, 0.f};
            f32x4 a3a = {bg3, bg3, bg3, bg3}, a3b = {0.f, 0.f, 0.f, 0.f};
            a1a = __builtin_amdgcn_mfma_f32_16x16x32_f16(Z0, Bg0[0], a1a, 0, 0, 0);
            a2a = __builtin_amdgcn_mfma_f32_16x16x32_f16(Z0, Bg1[0], a2a, 0, 0, 0);
            a3a = __builtin_amdgcn_mfma_f32_16x16x32_f16(Z0, Bg2[0], a3a, 0, 0, 0);
            a1b = __builtin_amdgcn_mfma_f32_16x16x32_f16(Z1, Bg0[1], a1b, 0, 0, 0);
            a2b = __builtin_amdgcn_mfma_f32_16x16x32_f16(Z1, Bg1[1], a2b, 0, 0, 0);
            a3b = __builtin_amdgcn_mfma_f32_16x16x32_f16(Z1, Bg2[1], a3b, 0, 0, 0);
            a1a = __builtin_amdgcn_mfma_f32_16x16x32_f16(Z2, Bg0[2], a1a, 0, 0, 0);
            a2a = __builtin_amdgcn_mfma_f32_16x16x32_f16(Z2, Bg1[2], a2a, 0, 0, 0);
            a3a = __builtin_amdgcn_mfma_f32_16x16x32_f16(Z2, Bg2[2], a3a, 0, 0, 0);
            a1b = __builtin_amdgcn_mfma_f32_16x16x32_f16(Z3, Bg0[3], a1b, 0, 0, 0);
            a2b = __builtin_amdgcn_mfma_f32_16x16x32_f16(Z3, Bg1[3], a2b, 0, 0, 0);
            a3b = __builtin_amdgcn_mfma_f32_16x16x32_f16(Z3, Bg2[3], a3b, 0, 0, 0);

            float p0 = __shfl(a1a[0] + a1b[0], srcl), p1 = __shfl(a1a[1] + a1b[1], srcl);
            float p2 = __shfl(a1a[2] + a1b[2], srcl), p3 = __shfl(a1a[3] + a1b[3], srcl);
            float q01 = (hi & 1) ? p1 : p0, q23 = (hi & 1) ? p3 : p2;
            v1 = (hi & 2) ? q23 : q01;
            p0 = __shfl(a2a[0] + a2b[0], srcl); p1 = __shfl(a2a[1] + a2b[1], srcl);
            p2 = __shfl(a2a[2] + a2b[2], srcl); p3 = __shfl(a2a[3] + a2b[3], srcl);
            q01 = (hi & 1) ? p1 : p0; q23 = (hi & 1) ? p3 : p2;
            v2 = (hi & 2) ? q23 : q01;
            p0 = __shfl(a3a[0] + a3b[0], srcl); p1 = __shfl(a3a[1] + a3b[1], srcl);
            p2 = __shfl(a3a[2] + a3b[2], srcl); p3 = __shfl(a3a[3] + a3b[3], srcl);
            q01 = (hi & 1) ? p1 : p0; q23 = (hi & 1) ? p3 : p2;
            v3 = (hi & 2) ? q23 : q01;
        } else {
            f32x4 a1 = {bg1, bg1, bg1, bg1};
            f32x4 a2 = {bg2, bg2, bg2, bg2};
            f32x4 a3 = {bg3, bg3, bg3, bg3};
            a1 = __builtin_amdgcn_mfma_f32_16x16x32_f16(Z0, Bg0[0], a1, 0, 0, 0);
            a2 = __builtin_amdgcn_mfma_f32_16x16x32_f16(Z0, Bg1[0], a2, 0, 0, 0);
            a3 = __builtin_amdgcn_mfma_f32_16x16x32_f16(Z0, Bg2[0], a3, 0, 0, 0);
            a1 = __builtin_amdgcn_mfma_f32_16x16x32_f16(Z1, Bg0[1], a1, 0, 0, 0);
            a2 = __builtin_amdgcn_mfma_f32_16x16x32_f16(Z1, Bg1[1], a2, 0, 0, 0);
            a3 = __builtin_amdgcn_mfma_f32_16x16x32_f16(Z1, Bg2[1], a3, 0, 0, 0);
            a1 = __builtin_amdgcn_mfma_f32_16x16x32_f16(Z2, Bg0[2], a1, 0, 0, 0);
            a2 = __builtin_amdgcn_mfma_f32_16x16x32_f16(Z2, Bg1[2], a2, 0, 0, 0);
            a3 = __builtin_amdgcn_mfma_f32_16x16x32_f16(Z2, Bg2[2], a3, 0, 0, 0);
            a1 = __builtin_amdgcn_mfma_f32_16x16x32_f16(Z3, Bg0[3], a1, 0, 0, 0);
            a2 = __builtin_amdgcn_mfma_f32_16x16x32_f16(Z3, Bg1[3], a2, 0, 0, 0);
            a3 = __builtin_amdgcn_mfma_f32_16x16x32_f16(Z3, Bg2[3], a3, 0, 0, 0);

            float p0 = __shfl(a1[0], srcl), p1 = __shfl(a1[1], srcl);
            float p2 = __shfl(a1[2], srcl), p3 = __shfl(a1[3], srcl);
            float q01 = (hi & 1) ? p1 : p0, q23 = (hi & 1) ? p3 : p2;
            v1 = (hi & 2) ? q23 : q01;
            p0 = __shfl(a2[0], srcl); p1 = __shfl(a2[1], srcl);
            p2 = __shfl(a2[2], srcl); p3 = __shfl(a2[3], srcl);
            q01 = (hi & 1) ? p1 : p0; q23 = (hi & 1) ? p3 : p2;
            v2 = (hi & 2) ? q23 : q01;
            p0 = __shfl(a3[0], srcl); p1 = __shfl(a3[1], srcl);
            p2 = __shfl(a3[2], srcl); p3 = __shfl(a3[3], srcl);
            q01 = (hi & 1) ? p1 : p0; q23 = (hi & 1) ? p3 : p2;
            v3 = (hi & 2) ? q23 : q01;
        }

        {
            float r1 = frcp(fexp2(2.8853901f * v1) + 1.0f);
            float ff1 = fmaf(-2.0f, r1, 1.0f);
            float r2 = frcp(fexp2(2.8853901f * v2) + 1.0f);
            float ff2 = fmaf(-2.0f, r2, 1.0f);
            float ti = frcp(1.0f + fexp2(-1.44269504f * v3));
            _Float16 hv = (_Float16)(ff1 + ti * (ff2 - ff1));
            zin[hi][HOFF + colB] = hv;
            if (MODE >= 1)
                hist[((size_t)(b0 + hi) * T_STEPS + t) * H + colB] = hv;
        }

        if constexpr (MODE < 2) {
            if (w < 2 && t + 1 < T_STEPS) {
                zin[rX][cX] = (_Float16)oxA;
                oxA = oxB;
                const int tf = t + 3;
                oxB = (tf < T_STEPS) ? obs[((size_t)(b0 + rX) * T_STEPS + tf) * OBS + cX] : 0.0f;
            }
        }
        sync_lds();
    }

    if constexpr (MODE >= 1) {
        // ---- epilogue: heads GEMM over this block's 4 rows x 1024 steps ----
        __syncthreads();                      // drains vmcnt: hist visible
        half8 Bh2[4];
#pragma unroll
        for (int ks = 0; ks < 4; ++ks)
#pragma unroll
            for (int j = 0; j < 8; ++j) {
                int k = ks * 32 + hi * 8 + j;
                float v = (lo < 8) ? Wa[k * A_DIM + lo] : ((lo == 8) ? Wc[k] : 0.0f);
                Bh2[ks][j] = (_Float16)v;
            }
        const float bh2 = (lo < 8) ? ba[lo] : ((lo == 8) ? bc[0] : 0.0f);

        for (int c = w; c < 256; c += NW) {   // 32 chunks per wave
            const int r = c >> 6;             // row 0..3
            const int s0 = (c & 63) << 4;     // step base (16 steps per tile)
            const _Float16* hp = hist + ((size_t)(b0 + r) * T_STEPS + (s0 + lo)) * H + hi * 8;
            half8 A0 = *(const half8*)(hp);
            half8 A1 = *(const half8*)(hp + 32);
            half8 A2 = *(const half8*)(hp + 64);
            half8 A3 = *(const half8*)(hp + 96);
            f32x4 acc = {bh2, bh2, bh2, bh2};
            acc = __builtin_amdgcn_mfma_f32_16x16x32_f16(A0, Bh2[0], acc, 0, 0, 0);
            acc = __builtin_amdgcn_mfma_f32_16x16x32_f16(A1, Bh2[1], acc, 0, 0, 0);
            acc = __builtin_amdgcn_mfma_f32_16x16x32_f16(A2, Bh2[2], acc, 0, 0, 0);
            acc = __builtin_amdgcn_mfma_f32_16x16x32_f16(A3, Bh2[3], acc, 0, 0, 0);
            if (lo < 9) {
#pragma unroll
                for (int j = 0; j < 4; ++j) {
                    const int s_ = s0 + hi * 4 + j;
                    if (lo < 8) out_mean[((size_t)(b0 + r) * T_STEPS + s_) * A_DIM + lo] = acc[j];
                    else        out_value[(size_t)(b0 + r) * T_STEPS + s_] = acc[j];
                }
            }
        }
    } else {
        // ---- fallback epilogue: heads for s = T-1 ----
        if (w == 7) {
            half8 A1 = *(const half8*)&zin[lo][32 + 0 * 32 + hi * 8];
            half8 A2 = *(const half8*)&zin[lo][32 + 1 * 32 + hi * 8];
            half8 A3 = *(const half8*)&zin[lo][32 + 2 * 32 + hi * 8];
            half8 A4 = *(const half8*)&zin[lo][32 + 3 * 32 + hi * 8];
            f32x4 acch = {bh, bh, bh, bh};
            acch = __builtin_amdgcn_mfma_f32_16x16x32_f16(A1, Bh[0], acch, 0, 0, 0);
            acch = __builtin_amdgcn_mfma_f32_16x16x32_f16(A2, Bh[1], acch, 0, 0, 0);
            acch = __builtin_amdgcn_mfma_f32_16x16x32_f16(A3, Bh[2], acch, 0, 0, 0);
            acch = __builtin_amdgcn_mfma_f32_16x16x32_f16(A4, Bh[3], acch, 0, 0, 0);
            if (hi == 0 && lo < 9) {
#pragma unroll
                for (int j = 0; j < 4; ++j) {
                    if (lo < 8) out_mean[((size_t)(b0 + j) * T_STEPS + (T_STEPS - 1)) * A_DIM + lo] = acch[j];
                    else        out_value[(size_t)(b0 + j) * T_STEPS + (T_STEPS - 1)] = acch[j];
                }
            }
        }
    }
}

extern "C" void kernel_launch(void* const* d_in, const int* in_sizes, int n_in,
                              void* d_out, int out_size, void* d_ws, size_t ws_size,
                              hipStream_t stream) {
    (void)in_sizes; (void)n_in; (void)out_size;
    const float* obs  = (const float*)d_in[0];
    const float* Wb   = (const float*)d_in[1];
    const float* bb   = (const float*)d_in[2];
    const float* Wff1 = (const float*)d_in[3];
    const float* bff1 = (const float*)d_in[4];
    const float* Wff2 = (const float*)d_in[5];
    const float* bff2 = (const float*)d_in[6];
    const float* Wta  = (const float*)d_in[7];
    const float* bta  = (const float*)d_in[8];
    const float* Wtb  = (const float*)d_in[9];
    const float* btb  = (const float*)d_in[10];
    const float* Wa   = (const float*)d_in[11];
    const float* ba   = (const float*)d_in[12];
    const float* Wc   = (const float*)d_in[13];
    const float* bc   = (const float*)d_in[14];
    float* out = (float*)d_out;
    float* out_mean  = out;
    float* out_value = out + (size_t)256 * 1024 * 8;

    const size_t one = (size_t)256 * 1024 * 128 * sizeof(_Float16);  // 67.1 MB
    _Float16* hist = (_Float16*)d_ws;
    _Float16* pxw  = hist + (size_t)256 * 1024 * 128;

    if (ws_size >= 2 * one) {
        cfc_kernel<2><<<dim3(NBLK), dim3(NT), 0, stream>>>(
            obs, Wb, bb, Wff1, bff1, Wff2, bff2, Wta, bta, Wtb, btb,
            Wa, ba, Wc, bc, out_mean, out_value, hist, pxw);
    } else if (ws_size >= one) {
        cfc_kernel<1><<<dim3(NBLK), dim3(NT), 0, stream>>>(
            obs, Wb, bb, Wff1, bff1, Wff2, bff2, Wta, bta, Wtb, btb,
            Wa, ba, Wc, bc, out_mean, out_value, hist, pxw);
    } else {
        cfc_kernel<0><<<dim3(NBLK), dim3(NT), 0, stream>>>(
            obs, Wb, bb, Wff1, bff1, Wff2, bff2, Wta, bta, Wtb, btb,
            Wa, ba, Wc, bc, out_mean, out_value, hist, pxw);
    }
}

// Round 17
// 1009.148 us; speedup vs baseline: 1.1473x; 1.1473x over previous
//
#include <hip/hip_runtime.h>

// CfC actor-critic forward: B=256, T=1024, OBS=32, H=128, A=8.
// R17 = revert to R15 (best verified: 1011 us). R16's px-hoist regressed
// (uncoalesced 2B/lane px loads, +160MB HBM traffic, serial prologue).
// Final structure: 64 blocks x 8 waves, 4 batch rows per block, M=16 MFMA
// tile, weights in registers, 2 LDS-only barriers/step, activations
// redistributed 1-per-lane, heads offloaded to a post-loop GEMM over the
// f16 h-history in d_ws. The remaining cost is the sequential
// 2048-interval LDS-exchange/dependency floor (~495 ns/interval).

typedef _Float16 half8 __attribute__((ext_vector_type(8)));
typedef float f32x4 __attribute__((ext_vector_type(4)));

#define T_STEPS 1024
#define OBS 32
#define H 128
#define A_DIM 8
#define NW 8
#define NT (NW * 64)
#define ROWS 4
#define NBLK 64

#define ZIN_P 164   // stride 82 words (mod 32 = 18) -> <=2-way banks
#define ZF_P 132    // stride 66 words (mod 32 = 2)

__device__ __forceinline__ float fexp2(float x) { return __builtin_amdgcn_exp2f(x); }
__device__ __forceinline__ float frcp(float x) { return __builtin_amdgcn_rcpf(x); }

// LDS-visibility barrier (no vmcnt drain; validated R10)
__device__ __forceinline__ void sync_lds() {
    __builtin_amdgcn_sched_barrier(0);
    asm volatile("s_waitcnt lgkmcnt(0)" ::: "memory");
    __builtin_amdgcn_s_barrier();
    __builtin_amdgcn_sched_barrier(0);
}

template<bool OFFLOAD>
__global__ void __launch_bounds__(NT) cfc_kernel(
    const float* __restrict__ obs,
    const float* __restrict__ Wb,  const float* __restrict__ bb,
    const float* __restrict__ Wff1, const float* __restrict__ bff1,
    const float* __restrict__ Wff2, const float* __restrict__ bff2,
    const float* __restrict__ Wta, const float* __restrict__ bta,
    const float* __restrict__ Wtb, const float* __restrict__ btb,
    const float* __restrict__ Wa,  const float* __restrict__ ba,
    const float* __restrict__ Wc,  const float* __restrict__ bc,
    float* __restrict__ out_mean, float* __restrict__ out_value,
    _Float16* __restrict__ hist)
{
    const int b0 = blockIdx.x * ROWS;
    const int tid = threadIdx.x;
    const int w = tid >> 6, l = tid & 63;
    const int lo = l & 15, hi = l >> 4;      // lo: M/N index, hi: k-group / row

    __shared__ _Float16 zin[16][ZIN_P];      // [x_t | h_{t-1}]
    __shared__ _Float16 zf[16][ZF_P];        // z(t)

    // ---------------- preload B-fragments (f16) ----------------
    const int colB = w * 16 + lo;

    half8 Bb[5];                              // backbone 160xH
#pragma unroll
    for (int ks = 0; ks < 5; ++ks)
#pragma unroll
        for (int j = 0; j < 8; ++j) {
            int k = ks * 32 + hi * 8 + j;
            Bb[ks][j] = (_Float16)Wb[k * H + colB];
        }
    const float bbv = bb[colB];

    half8 Bg0[4], Bg1[4], Bg2[4];             // gates HxH
#pragma unroll
    for (int ks = 0; ks < 4; ++ks)
#pragma unroll
        for (int j = 0; j < 8; ++j) {
            int k = ks * 32 + hi * 8 + j;
            Bg0[ks][j] = (_Float16)Wff1[k * H + colB];
            Bg1[ks][j] = (_Float16)Wff2[k * H + colB];
            Bg2[ks][j] = (_Float16)(Wta[k * H + colB] + Wtb[k * H + colB]);
        }
    const float bg1 = bff1[colB], bg2 = bff2[colB], bg3 = bta[colB] + btb[colB];

    // In-loop heads only for the fallback path (wave 7)
    half8 Bh[4];
    float bh = 0.f;
    if (!OFFLOAD && w == 7) {
#pragma unroll
        for (int ks = 0; ks < 4; ++ks)
#pragma unroll
            for (int j = 0; j < 8; ++j) {
                int k = ks * 32 + hi * 8 + j;
                float v = (lo < 8) ? Wa[k * A_DIM + lo] : ((lo == 8) ? Wc[k] : 0.0f);
                Bh[ks][j] = (_Float16)v;
            }
        bh = (lo < 8) ? ba[lo] : ((lo == 8) ? bc[0] : 0.0f);
    }

    // ---------------- init LDS (zin AND zf zeroed; rows 4-15 stay zero) ---
    for (int i = tid; i < 16 * ZIN_P; i += NT) (&zin[0][0])[i] = (_Float16)0.0f;
    for (int i = tid; i < 16 * ZF_P; i += NT) (&zf[0][0])[i] = (_Float16)0.0f;
    __syncthreads();
    const int rX = (w << 1) | (l >> 5), cX = l & 31;   // waves 0-1: rows 0-3
    if (w < 2) zin[rX][cX] = (_Float16)obs[((size_t)(b0 + rX) * T_STEPS) * OBS + cX];
    __syncthreads();

    // obs prefetch ring, 2 steps deep (waves 0-1)
    float oxA = 0.f, oxB = 0.f;
    if (w < 2) {
        oxA = obs[((size_t)(b0 + rX) * T_STEPS + 1) * OBS + cX];
        oxB = obs[((size_t)(b0 + rX) * T_STEPS + 2) * OBS + cX];
    }

    const int srcl = lo;                     // shuffle source: hi==0 lane of same col

    // ================= main loop: 2 LDS-only barriers/step =================
    for (int t = 0; t < T_STEPS; ++t) {
        // ---- phase 1: z = lecun_tanh([x|h] @ Wb + bb) ----
        half8 A0 = *(const half8*)&zin[lo][0 * 32 + hi * 8];
        half8 A1 = *(const half8*)&zin[lo][1 * 32 + hi * 8];
        half8 A2 = *(const half8*)&zin[lo][2 * 32 + hi * 8];
        half8 A3 = *(const half8*)&zin[lo][3 * 32 + hi * 8];
        half8 A4 = *(const half8*)&zin[lo][4 * 32 + hi * 8];
        f32x4 az0 = {bbv, bbv, bbv, bbv};
        f32x4 az1 = {0.f, 0.f, 0.f, 0.f};
        az0 = __builtin_amdgcn_mfma_f32_16x16x32_f16(A0, Bb[0], az0, 0, 0, 0);
        az1 = __builtin_amdgcn_mfma_f32_16x16x32_f16(A1, Bb[1], az1, 0, 0, 0);
        az0 = __builtin_amdgcn_mfma_f32_16x16x32_f16(A2, Bb[2], az0, 0, 0, 0);
        az1 = __builtin_amdgcn_mfma_f32_16x16x32_f16(A3, Bb[3], az1, 0, 0, 0);
        az0 = __builtin_amdgcn_mfma_f32_16x16x32_f16(A4, Bb[4], az0, 0, 0, 0);

        if (!OFFLOAD && w == 7 && t > 0) {
            f32x4 acch = {bh, bh, bh, bh};
            acch = __builtin_amdgcn_mfma_f32_16x16x32_f16(A1, Bh[0], acch, 0, 0, 0);
            acch = __builtin_amdgcn_mfma_f32_16x16x32_f16(A2, Bh[1], acch, 0, 0, 0);
            acch = __builtin_amdgcn_mfma_f32_16x16x32_f16(A3, Bh[2], acch, 0, 0, 0);
            acch = __builtin_amdgcn_mfma_f32_16x16x32_f16(A4, Bh[3], acch, 0, 0, 0);
            if (hi == 0 && lo < 9) {
#pragma unroll
                for (int j = 0; j < 4; ++j) {
                    if (lo < 8) out_mean[((size_t)(b0 + j) * T_STEPS + (t - 1)) * A_DIM + lo] = acch[j];
                    else        out_value[(size_t)(b0 + j) * T_STEPS + (t - 1)] = acch[j];
                }
            }
        }

        // z-act (redistributed): real rows live in hi==0 lanes' 4 regs;
        // spread 64 values over 64 lanes -> 1 exp2 + 1 rcp per lane.
        {
            float s0 = az0[0] + az1[0];
            float s1 = az0[1] + az1[1];
            float s2 = az0[2] + az1[2];
            float s3 = az0[3] + az1[3];
            float p0 = __shfl(s0, srcl);
            float p1 = __shfl(s1, srcl);
            float p2 = __shfl(s2, srcl);
            float p3 = __shfl(s3, srcl);
            float q01 = (hi & 1) ? p1 : p0;
            float q23 = (hi & 1) ? p3 : p2;
            float sv  = (hi & 2) ? q23 : q01;
            float r = frcp(fexp2(1.9216697f * sv) + 1.0f);
            zf[hi][colB] = (_Float16)fmaf(-3.4318f, r, 1.7159f);   // row = hi (0..3)
        }
        sync_lds();

        // ---- phase 2: gates + combine -> h(t) ----
        half8 Z0 = *(const half8*)&zf[lo][0 * 32 + hi * 8];
        half8 Z1 = *(const half8*)&zf[lo][1 * 32 + hi * 8];
        half8 Z2 = *(const half8*)&zf[lo][2 * 32 + hi * 8];
        half8 Z3 = *(const half8*)&zf[lo][3 * 32 + hi * 8];
        f32x4 a1 = {bg1, bg1, bg1, bg1};
        f32x4 a2 = {bg2, bg2, bg2, bg2};
        f32x4 a3 = {bg3, bg3, bg3, bg3};
        a1 = __builtin_amdgcn_mfma_f32_16x16x32_f16(Z0, Bg0[0], a1, 0, 0, 0);
        a2 = __builtin_amdgcn_mfma_f32_16x16x32_f16(Z0, Bg1[0], a2, 0, 0, 0);
        a3 = __builtin_amdgcn_mfma_f32_16x16x32_f16(Z0, Bg2[0], a3, 0, 0, 0);
        a1 = __builtin_amdgcn_mfma_f32_16x16x32_f16(Z1, Bg0[1], a1, 0, 0, 0);
        a2 = __builtin_amdgcn_mfma_f32_16x16x32_f16(Z1, Bg1[1], a2, 0, 0, 0);
        a3 = __builtin_amdgcn_mfma_f32_16x16x32_f16(Z1, Bg2[1], a3, 0, 0, 0);
        a1 = __builtin_amdgcn_mfma_f32_16x16x32_f16(Z2, Bg0[2], a1, 0, 0, 0);
        a2 = __builtin_amdgcn_mfma_f32_16x16x32_f16(Z2, Bg1[2], a2, 0, 0, 0);
        a3 = __builtin_amdgcn_mfma_f32_16x16x32_f16(Z2, Bg2[2], a3, 0, 0, 0);
        a1 = __builtin_amdgcn_mfma_f32_16x16x32_f16(Z3, Bg0[3], a1, 0, 0, 0);
        a2 = __builtin_amdgcn_mfma_f32_16x16x32_f16(Z3, Bg1[3], a2, 0, 0, 0);
        a3 = __builtin_amdgcn_mfma_f32_16x16x32_f16(Z3, Bg2[3], a3, 0, 0, 0);

        // gate activations (redistributed): 3 exp2 + 3 rcp per lane total.
        {
            float p0 = __shfl(a1[0], srcl), p1 = __shfl(a1[1], srcl);
            float p2 = __shfl(a1[2], srcl), p3 = __shfl(a1[3], srcl);
            float q01 = (hi & 1) ? p1 : p0, q23 = (hi & 1) ? p3 : p2;
            float v1 = (hi & 2) ? q23 : q01;

            p0 = __shfl(a2[0], srcl); p1 = __shfl(a2[1], srcl);
            p2 = __shfl(a2[2], srcl); p3 = __shfl(a2[3], srcl);
            q01 = (hi & 1) ? p1 : p0; q23 = (hi & 1) ? p3 : p2;
            float v2 = (hi & 2) ? q23 : q01;

            p0 = __shfl(a3[0], srcl); p1 = __shfl(a3[1], srcl);
            p2 = __shfl(a3[2], srcl); p3 = __shfl(a3[3], srcl);
            q01 = (hi & 1) ? p1 : p0; q23 = (hi & 1) ? p3 : p2;
            float v3 = (hi & 2) ? q23 : q01;

            float r1 = frcp(fexp2(2.8853901f * v1) + 1.0f);
            float ff1 = fmaf(-2.0f, r1, 1.0f);
            float r2 = frcp(fexp2(2.8853901f * v2) + 1.0f);
            float ff2 = fmaf(-2.0f, r2, 1.0f);
            float ti = frcp(1.0f + fexp2(-1.44269504f * v3));
            _Float16 hv = (_Float16)(ff1 + ti * (ff2 - ff1));
            zin[hi][32 + colB] = hv;                         // row = hi (0..3)
            if (OFFLOAD)
                hist[((size_t)(b0 + hi) * T_STEPS + t) * H + colB] = hv;
        }

        // x(t+1) -> zin (waves 0-1), refill 2-deep ring
        if (w < 2 && t + 1 < T_STEPS) {
            zin[rX][cX] = (_Float16)oxA;
            oxA = oxB;
            const int tf = t + 3;
            oxB = (tf < T_STEPS) ? obs[((size_t)(b0 + rX) * T_STEPS + tf) * OBS + cX] : 0.0f;
        }
        sync_lds();
    }

    if (OFFLOAD) {
        // ---- epilogue: heads GEMM over this block's 4 rows x 1024 steps ----
        __syncthreads();                      // drains vmcnt: hist visible
        half8 Bh2[4];
#pragma unroll
        for (int ks = 0; ks < 4; ++ks)
#pragma unroll
            for (int j = 0; j < 8; ++j) {
                int k = ks * 32 + hi * 8 + j;
                float v = (lo < 8) ? Wa[k * A_DIM + lo] : ((lo == 8) ? Wc[k] : 0.0f);
                Bh2[ks][j] = (_Float16)v;
            }
        const float bh2 = (lo < 8) ? ba[lo] : ((lo == 8) ? bc[0] : 0.0f);

        for (int c = w; c < 256; c += NW) {   // 32 chunks per wave
            const int r = c >> 6;             // row 0..3
            const int s0 = (c & 63) << 4;     // step base (16 steps per tile)
            const _Float16* hp = hist + ((size_t)(b0 + r) * T_STEPS + (s0 + lo)) * H + hi * 8;
            half8 A0 = *(const half8*)(hp);
            half8 A1 = *(const half8*)(hp + 32);
            half8 A2 = *(const half8*)(hp + 64);
            half8 A3 = *(const half8*)(hp + 96);
            f32x4 acc = {bh2, bh2, bh2, bh2};
            acc = __builtin_amdgcn_mfma_f32_16x16x32_f16(A0, Bh2[0], acc, 0, 0, 0);
            acc = __builtin_amdgcn_mfma_f32_16x16x32_f16(A1, Bh2[1], acc, 0, 0, 0);
            acc = __builtin_amdgcn_mfma_f32_16x16x32_f16(A2, Bh2[2], acc, 0, 0, 0);
            acc = __builtin_amdgcn_mfma_f32_16x16x32_f16(A3, Bh2[3], acc, 0, 0, 0);
            if (lo < 9) {
#pragma unroll
                for (int j = 0; j < 4; ++j) {
                    const int s_ = s0 + hi * 4 + j;    // C-frag row = step offset
                    if (lo < 8) out_mean[((size_t)(b0 + r) * T_STEPS + s_) * A_DIM + lo] = acc[j];
                    else        out_value[(size_t)(b0 + r) * T_STEPS + s_] = acc[j];
                }
            }
        }
    } else {
        // ---- fallback epilogue: heads for s = T-1 ----
        if (w == 7) {
            half8 A1 = *(const half8*)&zin[lo][32 + 0 * 32 + hi * 8];
            half8 A2 = *(const half8*)&zin[lo][32 + 1 * 32 + hi * 8];
            half8 A3 = *(const half8*)&zin[lo][32 + 2 * 32 + hi * 8];
            half8 A4 = *(const half8*)&zin[lo][32 + 3 * 32 + hi * 8];
            f32x4 acch = {bh, bh, bh, bh};
            acch = __builtin_amdgcn_mfma_f32_16x16x32_f16(A1, Bh[0], acch, 0, 0, 0);
            acch = __builtin_amdgcn_mfma_f32_16x16x32_f16(A2, Bh[1], acch, 0, 0, 0);
            acch = __builtin_amdgcn_mfma_f32_16x16x32_f16(A3, Bh[2], acch, 0, 0, 0);
            acch = __builtin_amdgcn_mfma_f32_16x16x32_f16(A4, Bh[3], acch, 0, 0, 0);
            if (hi == 0 && lo < 9) {
#pragma unroll
                for (int j = 0; j < 4; ++j) {
                    if (lo < 8) out_mean[((size_t)(b0 + j) * T_STEPS + (T_STEPS - 1)) * A_DIM + lo] = acch[j];
                    else        out_value[(size_t)(b0 + j) * T_STEPS + (T_STEPS - 1)] = acch[j];
                }
            }
        }
    }
}

extern "C" void kernel_launch(void* const* d_in, const int* in_sizes, int n_in,
                              void* d_out, int out_size, void* d_ws, size_t ws_size,
                              hipStream_t stream) {
    (void)in_sizes; (void)n_in; (void)out_size;
    const float* obs  = (const float*)d_in[0];
    const float* Wb   = (const float*)d_in[1];
    const float* bb   = (const float*)d_in[2];
    const float* Wff1 = (const float*)d_in[3];
    const float* bff1 = (const float*)d_in[4];
    const float* Wff2 = (const float*)d_in[5];
    const float* bff2 = (const float*)d_in[6];
    const float* Wta  = (const float*)d_in[7];
    const float* bta  = (const float*)d_in[8];
    const float* Wtb  = (const float*)d_in[9];
    const float* btb  = (const float*)d_in[10];
    const float* Wa   = (const float*)d_in[11];
    const float* ba   = (const float*)d_in[12];
    const float* Wc   = (const float*)d_in[13];
    const float* bc   = (const float*)d_in[14];
    float* out = (float*)d_out;
    float* out_mean  = out;
    float* out_value = out + (size_t)256 * 1024 * 8;

    const size_t need = (size_t)256 * 1024 * 128 * sizeof(_Float16);  // 67.1 MB
    if (ws_size >= need) {
        cfc_kernel<true><<<dim3(NBLK), dim3(NT), 0, stream>>>(
            obs, Wb, bb, Wff1, bff1, Wff2, bff2, Wta, bta, Wtb, btb,
            Wa, ba, Wc, bc, out_mean, out_value, (_Float16*)d_ws);
    } else {
        cfc_kernel<false><<<dim3(NBLK), dim3(NT), 0, stream>>>(
            obs, Wb, bb, Wff1, bff1, Wff2, bff2, Wta, bta, Wtb, btb,
            Wa, ba, Wc, bc, out_mean, out_value, (_Float16*)d_ws);
    }
}